// Round 1
// baseline (97.237 us; speedup 1.0000x reference)
//
#include <hip/hip_runtime.h>

typedef __attribute__((ext_vector_type(8))) short short8;
typedef __attribute__((ext_vector_type(4))) float f32x4;

#define ROW_B 1056          // 66 w-slots * 16 bytes (8 bf16 channels)
#define SLOT_B 10560        // 10 h-rows per d-plane
#define NSLOT 4

__device__ __forceinline__ unsigned short f2bf(float f) {
  unsigned u = __builtin_bit_cast(unsigned, f);
  u += 0x7FFFu + ((u >> 16) & 1u);          // RNE (inputs finite)
  return (unsigned short)(u >> 16);
}

// grid: 512 = 64 b * 8 h-octets ; block: 256 (4 waves x 2 h'-rows each)
__launch_bounds__(256, 2)
__global__ void conv_fused(const float* __restrict__ x,
                           const float* __restrict__ cw,
                           float* __restrict__ ws) {
  __shared__ __align__(16) unsigned char smem[NSLOT * SLOT_B];
  __shared__ float wsum[4];

  const int bid = blockIdx.x;
  const int b   = bid >> 3;
  const int hq  = bid & 7;
  const int h0  = hq * 8;

  const int tid  = threadIdx.x;
  const int lane = tid & 63;
  const int wid  = tid >> 6;
  const int nm   = lane & 15;   // = n (cout) for B/C, m-index base for A
  const int g    = lane >> 4;

  const float* xb = x + (size_t)b * (8u * 32u * 64u * 64u);

  // ---- B fragments (weights) -> 28 VGPRs, once per block ----
  // B[k][n], lane: n = lane&15, k = 32*kstep + 8*g + j ; tap = 4*kstep+g, c = j
  short8 bfrag[7];
#pragma unroll
  for (int k = 0; k < 7; ++k) {
    const int tap = 4 * k + g;
    short8 f;
#pragma unroll
    for (int j = 0; j < 8; ++j) {
      float v = (tap < 27) ? cw[(nm * 8 + j) * 27 + tap] : 0.f;
      f[j] = (short)f2bf(v);
    }
    bfrag[k] = f;
  }

  // ---- A per-kstep address precompute (tap clamped: pad tap reads real data x 0-weight) ----
  int off0_[7], kd_[7];
#pragma unroll
  for (int k = 0; k < 7; ++k) {
    int tap = 4 * k + g; if (tap > 26) tap = 26;
    const int kd = tap / 9, r = tap - 9 * kd;
    const int kh = r / 3,  kw = r - 3 * kh;
    kd_[k]   = kd;
    off0_[k] = (2 * wid + kh) * ROW_B + (nm + kw) * 16;
  }

  // ---- staging: one d-plane (8c x 10h x 64w fp32) -> LDS [h][w][c] bf16 ----
  auto stage = [&](int p) {
    const int slot = p & 3;
#pragma unroll
    for (int pass = 0; pass < 3; ++pass) {
      const int t = tid + pass * 256;
      if (t < 640) {
        const int w4  = t & 15;
        const int rc  = t >> 4;        // 0..39
        const int row = rc % 10;
        const int cp  = rc / 10;       // channel pair 0..3
        const int h   = h0 + row;
        if (h < 64) {
          const float* s0 = xb + ((size_t)(2 * cp) * 32 + p) * 4096 + h * 64 + w4 * 4;
          const float4 a = *(const float4*)s0;
          const float4 c = *(const float4*)(s0 + 131072);   // next channel
          unsigned char* dst = smem + slot * SLOT_B + row * ROW_B + (w4 * 4) * 16 + cp * 4;
          *(unsigned*)(dst +  0) = (unsigned)f2bf(a.x) | ((unsigned)f2bf(c.x) << 16);
          *(unsigned*)(dst + 16) = (unsigned)f2bf(a.y) | ((unsigned)f2bf(c.y) << 16);
          *(unsigned*)(dst + 32) = (unsigned)f2bf(a.z) | ((unsigned)f2bf(c.z) << 16);
          *(unsigned*)(dst + 48) = (unsigned)f2bf(a.w) | ((unsigned)f2bf(c.w) << 16);
        }
      }
    }
  };

  stage(0);
  stage(1);

  const bool hvalid = !(hq == 7 && wid == 3);  // h' 62,63 invalid
  float sum = 0.f;
  float p01[4], p23[4];

  for (int dp = 0; dp < 30; ++dp) {
    stage(dp + 2);               // plane dp+2 <= 31 always exists
    __syncthreads();             // writes of plane dp+2 visible; ring slot being
                                 // written next iter (dp+3 == dp-1 mod 4) is not
                                 // read by compute(dp) -> one barrier suffices

    f32x4 acc[2][4];
    const f32x4 zero = {0.f, 0.f, 0.f, 0.f};
#pragma unroll
    for (int i = 0; i < 2; ++i)
#pragma unroll
      for (int w = 0; w < 4; ++w) acc[i][w] = zero;

#pragma unroll
    for (int k = 0; k < 7; ++k) {
      const int base = ((dp + kd_[k]) & 3) * SLOT_B + off0_[k];
#pragma unroll
      for (int hli = 0; hli < 2; ++hli) {
#pragma unroll
        for (int wt = 0; wt < 4; ++wt) {
          const short8 av = *(const short8*)(smem + base + hli * ROW_B + wt * 256);
          acc[hli][wt] = __builtin_amdgcn_mfma_f32_16x16x32_bf16(
              av, bfrag[k], acc[hli][wt], 0, 0, 0);
        }
      }
    }

    // pooling: all 8 window members in-register.
    // lane holds cout=nm, w' = wt*16 + 4g + r  (r = acc component)
#pragma unroll
    for (int wt = 0; wt < 4; ++wt) {
      const float e01 = fmaxf(fmaxf(acc[0][wt][0], acc[0][wt][1]),
                              fmaxf(acc[1][wt][0], acc[1][wt][1]));
      const float e23 = fmaxf(fmaxf(acc[0][wt][2], acc[0][wt][3]),
                              fmaxf(acc[1][wt][2], acc[1][wt][3]));
      if ((dp & 1) == 0) {
        p01[wt] = e01; p23[wt] = e23;
      } else if (hvalid) {
        sum += fmaxf(p01[wt], e01);
        if (!(wt == 3 && g == 3)) sum += fmaxf(p23[wt], e23);  // w' 62,63 invalid
      }
    }
  }

  // block reduce -> one partial per block
#pragma unroll
  for (int off = 32; off > 0; off >>= 1) sum += __shfl_down(sum, off);
  if (lane == 0) wsum[wid] = sum;
  __syncthreads();
  if (tid == 0) ws[bid] = wsum[0] + wsum[1] + wsum[2] + wsum[3];
}

// out[b] = 0.5 * S_b / 14415 + 0.5 * sum(conv_bias) + sum(bias)
__global__ void finalize_k(const float* __restrict__ ws,
                           const float* __restrict__ cb,
                           const float* __restrict__ bias,
                           float* __restrict__ out) {
  const int b = threadIdx.x;
  float s = 0.f;
#pragma unroll
  for (int hq = 0; hq < 8; ++hq) s += ws[b * 8 + hq];
  float cbs = 0.f, bs = 0.f;
#pragma unroll
  for (int c = 0; c < 16; ++c) { cbs += cb[c]; bs += bias[c]; }
  out[b] = 0.5f * s / 14415.f + 0.5f * cbs + bs;
}

extern "C" void kernel_launch(void* const* d_in, const int* in_sizes, int n_in,
                              void* d_out, int out_size, void* d_ws, size_t ws_size,
                              hipStream_t stream) {
  const float* x    = (const float*)d_in[0];
  const float* cw   = (const float*)d_in[1];
  const float* cb   = (const float*)d_in[2];
  const float* bias = (const float*)d_in[3];
  float* out = (float*)d_out;
  float* ws  = (float*)d_ws;   // 512 floats

  hipLaunchKernelGGL(conv_fused, dim3(512), dim3(256), 0, stream, x, cw, ws);
  hipLaunchKernelGGL(finalize_k, dim3(1), dim3(64), 0, stream, ws, cb, bias, out);
}

// Round 2
// 88.705 us; speedup vs baseline: 1.0962x; 1.0962x over previous
//
#include <hip/hip_runtime.h>

typedef __attribute__((ext_vector_type(8))) short short8;
typedef __attribute__((ext_vector_type(4))) float f32x4;

#define ROW_B 1056          // 66 w-chunks * 16 bytes (8 bf16 channels per chunk)
#define SLOT_B 10560        // 10 h-rows per d-plane
#define NSLOT 4

__device__ __forceinline__ unsigned short f2bf(float f) {
  unsigned u = __builtin_bit_cast(unsigned, f);
  u += 0x7FFFu + ((u >> 16) & 1u);          // RNE (inputs finite)
  return (unsigned short)(u >> 16);
}
__device__ __forceinline__ unsigned pk2(float lo, float hi) {
  return (unsigned)f2bf(lo) | ((unsigned)f2bf(hi) << 16);
}

#define MF(ACC, H, FR, KD, KH)                                                \
  ACC[H][wt] = __builtin_amdgcn_mfma_f32_16x16x32_bf16(FR, bfragB[KD][KH],    \
                                                       ACC[H][wt], 0, 0, 0)

// One plane dp: stage(dp+2), barrier, open AN (d'=dp), MFMA kd=0->AN,
// kd=1->AM (d'=dp-1), kd=2->AO (d'=dp-2), then close AO (pool).
#define PROC(DP, AN, AM, AO, K1, K2, DOCLOSE, SAVEP)                          \
  {                                                                           \
    const int dp_ = (DP);                                                     \
    if (dp_ + 2 <= 31) stage(dp_ + 2);                                        \
    __syncthreads();                                                          \
    _Pragma("unroll") for (int h_ = 0; h_ < 2; ++h_)                          \
      _Pragma("unroll") for (int w_ = 0; w_ < 4; ++w_) AN[h_][w_] = zf4;      \
    const int sb_ = (dp_ & 3) * SLOT_B + rowbase;                             \
    _Pragma("unroll") for (int wt = 0; wt < 4; ++wt) {                        \
      const short8 f0 = *(const short8*)(smem + sb_ + 0 * ROW_B + physoff[wt]); \
      const short8 f1 = *(const short8*)(smem + sb_ + 1 * ROW_B + physoff[wt]); \
      const short8 f2 = *(const short8*)(smem + sb_ + 2 * ROW_B + physoff[wt]); \
      const short8 f3 = *(const short8*)(smem + sb_ + 3 * ROW_B + physoff[wt]); \
      MF(AN, 0, f0, 0, 0); MF(AN, 1, f1, 0, 0);                               \
      MF(AN, 0, f1, 0, 1); MF(AN, 1, f2, 0, 1);                               \
      MF(AN, 0, f2, 0, 2); MF(AN, 1, f3, 0, 2);                               \
      if (K1) {                                                               \
        MF(AM, 0, f0, 1, 0); MF(AM, 1, f1, 1, 0);                             \
        MF(AM, 0, f1, 1, 1); MF(AM, 1, f2, 1, 1);                             \
        MF(AM, 0, f2, 1, 2); MF(AM, 1, f3, 1, 2);                             \
      }                                                                       \
      if (K2) {                                                               \
        MF(AO, 0, f0, 2, 0); MF(AO, 1, f1, 2, 0);                             \
        MF(AO, 0, f1, 2, 1); MF(AO, 1, f2, 2, 1);                             \
        MF(AO, 0, f2, 2, 2); MF(AO, 1, f3, 2, 2);                             \
      }                                                                       \
    }                                                                         \
    if (DOCLOSE) {                                                            \
      _Pragma("unroll") for (int wt = 0; wt < 4; ++wt) {                      \
        const float e01 = fmaxf(fmaxf(AO[0][wt][0], AO[0][wt][1]),            \
                                fmaxf(AO[1][wt][0], AO[1][wt][1]));           \
        const float e23 = fmaxf(fmaxf(AO[0][wt][2], AO[0][wt][3]),            \
                                fmaxf(AO[1][wt][2], AO[1][wt][3]));           \
        if (SAVEP) {                                                          \
          p01[wt] = e01; p23[wt] = e23;                                       \
        } else if (hvalid) {                                                  \
          sum += fmaxf(p01[wt], e01);                                         \
          if (!(wt == 3 && g == 3)) sum += fmaxf(p23[wt], e23);               \
        }                                                                     \
      }                                                                       \
    }                                                                         \
  }

// grid: 512 = 64 b * 8 h-octets ; block: 256 (4 waves x 2 h'-rows each)
__launch_bounds__(256, 2)
__global__ void conv_fused(const float* __restrict__ x,
                           const float* __restrict__ cw,
                           float* __restrict__ ws) {
  __shared__ __align__(16) unsigned char smem[NSLOT * SLOT_B];
  __shared__ float wsum[4];

  const int bid = blockIdx.x;
  const int b   = bid >> 3;
  const int hq  = bid & 7;
  const int h0  = hq * 8;

  const int tid  = threadIdx.x;
  const int lane = tid & 63;
  const int wid  = tid >> 6;
  const int nm   = lane & 15;
  const int g    = lane >> 4;

  const float* xb = x + (size_t)b * (8u * 32u * 64u * 64u);

  // ---- B fragments: 9 (kd,kh) weight-sets, K = kw*8 + c (24 used, 8 pad) ----
  // B[k][n]: n = lane&15 = cout, k = 8*g + j -> kw = g (g<3), c = j
  short8 bfragB[3][3];
#pragma unroll
  for (int kd = 0; kd < 3; ++kd)
#pragma unroll
    for (int kh = 0; kh < 3; ++kh) {
      short8 f;
#pragma unroll
      for (int j = 0; j < 8; ++j) {
        float v = (g < 3) ? cw[(nm * 8 + j) * 27 + kd * 9 + kh * 3 + g] : 0.f;
        f[j] = (short)f2bf(v);
      }
      bfragB[kd][kh] = f;
    }

  // ---- A-fragment chunk offsets (XOR-swizzled), one per w-tile ----
  const int gc = (g < 3) ? g : 2;     // pad lanes read real data, weight = 0
  int physoff[4];
#pragma unroll
  for (int wt = 0; wt < 4; ++wt) {
    const int c = wt * 16 + nm + gc;
    physoff[wt] = (c ^ ((c >> 3) & 7)) * 16;
  }
  const int rowbase = (2 * wid) * ROW_B;

  // ---- staging precompute: 3 passes of 256 threads cover 640 slots ----
  bool st_act[3]; const float* st_src[3];
  int st_d0[3], st_d1[3], st_d2[3], st_d3[3];
#pragma unroll
  for (int pass = 0; pass < 3; ++pass) {
    const int t = tid + pass * 256;
    bool act = (t < 640);
    const int w4  = t & 15;
    const int rc  = (t >> 4) % 40;
    const int row = rc % 10;
    const int cp  = rc / 10;
    int h = h0 + row;
    if (h > 63) { act = false; h = 63; }
    st_act[pass] = act;
    st_src[pass] = xb + (size_t)(2 * cp) * 131072 + h * 64 + w4 * 4;
    const int q  = (w4 >> 1) & 7;
    const int c0 = 4 * w4;
    const int db = row * ROW_B + cp * 4;
    st_d0[pass] = db + ((c0 + 0) ^ q) * 16;
    st_d1[pass] = db + ((c0 + 1) ^ q) * 16;
    st_d2[pass] = db + ((c0 + 2) ^ q) * 16;
    st_d3[pass] = db + ((c0 + 3) ^ q) * 16;
  }

  auto stage = [&](int p) {
    unsigned char* d = smem + (p & 3) * SLOT_B;
#pragma unroll
    for (int pass = 0; pass < 3; ++pass) {
      if (st_act[pass]) {
        const float* s0 = st_src[pass] + p * 4096;
        const float4 a = *(const float4*)s0;
        const float4 c = *(const float4*)(s0 + 131072);
        *(unsigned*)(d + st_d0[pass]) = pk2(a.x, c.x);
        *(unsigned*)(d + st_d1[pass]) = pk2(a.y, c.y);
        *(unsigned*)(d + st_d2[pass]) = pk2(a.z, c.z);
        *(unsigned*)(d + st_d3[pass]) = pk2(a.w, c.w);
      }
    }
  };

  const bool hvalid = !(hq == 7 && wid == 3);  // h' 62,63 invalid
  const f32x4 zf4 = {0.f, 0.f, 0.f, 0.f};
  float sum = 0.f;
  float p01[4], p23[4];
  f32x4 accA[2][4], accB[2][4], accC[2][4];    // d' % 3 -> A,B,C

  stage(0);
  stage(1);

  // prologue: planes 0,1 (no closures yet)
  PROC(0, accA, accB, accC, 0, 0, 0, 0)
  PROC(1, accB, accA, accC, 1, 0, 0, 0)

  // main: planes 2..31, closures d' = 0..29 in order (even=save, odd=combine)
  for (int p0 = 2; p0 <= 26; p0 += 6) {
    PROC(p0 + 0, accC, accB, accA, 1, 1, 1, 1)
    PROC(p0 + 1, accA, accC, accB, 1, 1, 1, 0)
    PROC(p0 + 2, accB, accA, accC, 1, 1, 1, 1)
    PROC(p0 + 3, accC, accB, accA, 1, 1, 1, 0)
    PROC(p0 + 4, accA, accC, accB, 1, 1, 1, 1)
    PROC(p0 + 5, accB, accA, accC, 1, 1, 1, 0)
  }

  // block reduce -> one partial per block
#pragma unroll
  for (int off = 32; off > 0; off >>= 1) sum += __shfl_down(sum, off);
  if (lane == 0) wsum[wid] = sum;
  __syncthreads();
  if (tid == 0) ws[bid] = wsum[0] + wsum[1] + wsum[2] + wsum[3];
}

// out[b] = 0.5 * S_b / 14415 + 0.5 * sum(conv_bias) + sum(bias)
__global__ void finalize_k(const float* __restrict__ ws,
                           const float* __restrict__ cb,
                           const float* __restrict__ bias,
                           float* __restrict__ out) {
  const int b = threadIdx.x;
  float s = 0.f;
#pragma unroll
  for (int hq = 0; hq < 8; ++hq) s += ws[b * 8 + hq];
  float cbs = 0.f, bs = 0.f;
#pragma unroll
  for (int c = 0; c < 16; ++c) { cbs += cb[c]; bs += bias[c]; }
  out[b] = 0.5f * s / 14415.f + 0.5f * cbs + bs;
}

extern "C" void kernel_launch(void* const* d_in, const int* in_sizes, int n_in,
                              void* d_out, int out_size, void* d_ws, size_t ws_size,
                              hipStream_t stream) {
  const float* x    = (const float*)d_in[0];
  const float* cw   = (const float*)d_in[1];
  const float* cb   = (const float*)d_in[2];
  const float* bias = (const float*)d_in[3];
  float* out = (float*)d_out;
  float* ws  = (float*)d_ws;   // 512 floats

  hipLaunchKernelGGL(conv_fused, dim3(512), dim3(256), 0, stream, x, cw, ws);
  hipLaunchKernelGGL(finalize_k, dim3(1), dim3(64), 0, stream, ws, cb, bias, out);
}